// Round 5
// baseline (266.101 us; speedup 1.0000x reference)
//
#include <hip/hip_runtime.h>
#include <math.h>

// Problem constants
constexpr int NBATCH = 2, HH = 128, WW = 128, CC = 256;
constexpr int PP = 9, OMW = 108;            // om width = G*P*3 = 108
constexpr int MM = NBATCH * HH * WW;        // 32768 pixels
constexpr int BTCOLS = 640;                 // 256 (W_in) + 128 (W_om pad) + 256 (W_out)

using bf8 = __attribute__((ext_vector_type(8))) short;    // 8 bf16 = 4 VGPR
using f32x4 = __attribute__((ext_vector_type(4))) float;  // 4 f32 accum

__device__ __forceinline__ short f2bf(float x) {
  unsigned u = __builtin_bit_cast(unsigned, x);
  unsigned r = (u + 0x7fffu + ((u >> 16) & 1u)) >> 16;  // round-nearest-even
  return (short)r;
}
__device__ __forceinline__ float bf2f(short h) {
  unsigned u = ((unsigned)(unsigned short)h) << 16;
  return __builtin_bit_cast(float, u);
}
__device__ __forceinline__ void split4(float4 v, short4* h, short4* l) {
  short4 hh = make_short4(f2bf(v.x), f2bf(v.y), f2bf(v.z), f2bf(v.w));
  *h = hh;
  *l = make_short4(f2bf(v.x - bf2f(hh.x)), f2bf(v.y - bf2f(hh.y)),
                   f2bf(v.z - bf2f(hh.z)), f2bf(v.w - bf2f(hh.w)));
}

// ---------------------------------------------------------------------------
// Weight prep: transpose W (K-major -> col-major, K contiguous) and split
// f32 = hi(bf16) + lo(bf16). Cols [0,256)=W_in^T, [256,384)=W_om^T (pad 108
// ->128 with zeros), [384,640)=W_out^T. Row stride = 256 (K).
// ---------------------------------------------------------------------------
__global__ __launch_bounds__(256) void prep_kernel(
    const float* __restrict__ Win, const float* __restrict__ Wom,
    const float* __restrict__ Wout, short* __restrict__ Bh,
    short* __restrict__ Bl) {
  int gid = blockIdx.x * 256 + threadIdx.x;  // over BTCOLS*256
  int col = gid >> 8, k = gid & 255;
  float w;
  if (col < 256)
    w = Win[k * 256 + col];
  else if (col < 384) {
    int c = col - 256;
    w = (c < OMW) ? Wom[k * OMW + c] : 0.f;
  } else {
    int c = col - 384;
    w = Wout[k * 256 + c];
  }
  short h = f2bf(w);
  Bh[gid] = h;
  Bl[gid] = f2bf(w - bf2f(h));
}

// ---------------------------------------------------------------------------
// f32 -> bf16 hi/lo split (for sampled_feat). One thread per 4 elements.
// ---------------------------------------------------------------------------
__global__ __launch_bounds__(256) void split_kernel(
    const float* __restrict__ x, short* __restrict__ h,
    short* __restrict__ l) {
  int gid = blockIdx.x * 256 + threadIdx.x;  // over MM*64
  float4 v = *(const float4*)&x[(size_t)gid * 4];
  short4 hh, ll;
  split4(v, &hh, &ll);
  *(short4*)&h[(size_t)gid * 4] = hh;
  *(short4*)&l[(size_t)gid * 4] = ll;
}

// ---------------------------------------------------------------------------
// Depthwise 3x3 conv (pad 1) + bias -> bf16 hi/lo output.
// ---------------------------------------------------------------------------
__global__ __launch_bounds__(256) void dwconv_kernel(
    const float* __restrict__ x, const float* __restrict__ k,
    const float* __restrict__ b, short* __restrict__ yh,
    short* __restrict__ yl) {
  int gid = blockIdx.x * 256 + threadIdx.x;  // over MM * 64
  int q = gid & 63;
  int m = gid >> 6;
  int c = q * 4;
  int w = m & 127, h = (m >> 7) & 127, n = m >> 14;
  float4 acc = *(const float4*)&b[c];
#pragma unroll
  for (int dy = 0; dy < 3; ++dy) {
    int yy = h + dy - 1;
    if (yy < 0 || yy >= HH) continue;
#pragma unroll
    for (int dx = 0; dx < 3; ++dx) {
      int xx = w + dx - 1;
      if (xx < 0 || xx >= WW) continue;
      float4 v = *(const float4*)&x[(((size_t)n * HH + yy) * WW + xx) * CC + c];
      float4 kk = *(const float4*)&k[(dy * 3 + dx) * CC + c];
      acc.x += v.x * kk.x;
      acc.y += v.y * kk.y;
      acc.z += v.z * kk.z;
      acc.w += v.w * kk.w;
    }
  }
  short4 hh, ll;
  split4(acc, &hh, &ll);
  *(short4*)&yh[(size_t)m * CC + c] = hh;
  *(short4*)&yl[(size_t)m * CC + c] = ll;
}

// ---------------------------------------------------------------------------
// MFMA GEMM, bf16x3 split precision, pre-split A and B.
// Co[M x nout] = A[M,256] @ W[256,nout] (+bias). BM=64, BN=128, BK=64.
// 256 threads = 4 waves (2m x 2n), each wave 32x64 = 2x4 frags of 16x16x32.
// LDS stride SK=68 shorts (136B) -> 2-way banks max (free). 52KB -> 3 blk/CU.
// Frag maps (m89 convention): A row=lane&15, k=(lane>>4)*8+j; B col=lane&15;
// D col=lane&15, row=(lane>>4)*4+reg.
// ---------------------------------------------------------------------------
template <bool GUARD, bool BIAS>
__global__ __launch_bounds__(256, 3) void mgemm(
    const short* __restrict__ Ath, const short* __restrict__ Atl,
    const short* __restrict__ Bth, const short* __restrict__ Btl,
    const float* __restrict__ bias, float* __restrict__ Co, int nshift,
    int nout) {
  constexpr int BM = 64, BN = 128, BK = 64, SK = 68;
  __shared__ __align__(16) short As[2][BM * SK];
  __shared__ __align__(16) short Bs[2][BN * SK];
  const int t = threadIdx.x;
  const int lane = t & 63, wid = t >> 6;
  const int wr = wid >> 1, wc = wid & 1;
  const int l15 = lane & 15, l4 = lane >> 4;
  const int mb = ((int)blockIdx.x >> nshift) * BM;
  const int nb = ((int)blockIdx.x & ((1 << nshift) - 1)) * BN;

  f32x4 acc[2][4];
#pragma unroll
  for (int r = 0; r < 2; ++r)
#pragma unroll
    for (int n = 0; n < 4; ++n) acc[r][n] = (f32x4){0.f, 0.f, 0.f, 0.f};

  for (int ks = 0; ks < 256; ks += BK) {
    // Stage A: 64 rows x 8 16B-chunks, hi+lo
#pragma unroll
    for (int i = 0; i < 2; ++i) {
      int idx = t + 256 * i;
      int row = idx >> 3, kq = (idx & 7) * 8;
      size_t g = (size_t)(mb + row) * 256 + ks + kq;
      *(bf8*)&As[0][row * SK + kq] = *(const bf8*)&Ath[g];
      *(bf8*)&As[1][row * SK + kq] = *(const bf8*)&Atl[g];
    }
    // Stage B: 128 cols x 8 chunks, hi+lo
#pragma unroll
    for (int i = 0; i < 4; ++i) {
      int idx = t + 256 * i;
      int col = idx >> 3, kq = (idx & 7) * 8;
      size_t g = (size_t)(nb + col) * 256 + ks + kq;
      *(bf8*)&Bs[0][col * SK + kq] = *(const bf8*)&Bth[g];
      *(bf8*)&Bs[1][col * SK + kq] = *(const bf8*)&Btl[g];
    }
    __syncthreads();
#pragma unroll
    for (int kk = 0; kk < 2; ++kk) {
      int ko = kk * 32 + l4 * 8;
      bf8 ah[2], al[2], bh[4], bl[4];
#pragma unroll
      for (int r = 0; r < 2; ++r) {
        int row = wr * 32 + r * 16 + l15;
        ah[r] = *(const bf8*)&As[0][row * SK + ko];
        al[r] = *(const bf8*)&As[1][row * SK + ko];
      }
#pragma unroll
      for (int n = 0; n < 4; ++n) {
        int col = wc * 64 + n * 16 + l15;
        bh[n] = *(const bf8*)&Bs[0][col * SK + ko];
        bl[n] = *(const bf8*)&Bs[1][col * SK + ko];
      }
#pragma unroll
      for (int r = 0; r < 2; ++r)
#pragma unroll
        for (int n = 0; n < 4; ++n) {
          acc[r][n] = __builtin_amdgcn_mfma_f32_16x16x32_bf16(al[r], bh[n],
                                                              acc[r][n], 0, 0, 0);
          acc[r][n] = __builtin_amdgcn_mfma_f32_16x16x32_bf16(ah[r], bl[n],
                                                              acc[r][n], 0, 0, 0);
          acc[r][n] = __builtin_amdgcn_mfma_f32_16x16x32_bf16(ah[r], bh[n],
                                                              acc[r][n], 0, 0, 0);
        }
    }
    __syncthreads();
  }

#pragma unroll
  for (int r = 0; r < 2; ++r)
#pragma unroll
    for (int reg = 0; reg < 4; ++reg) {
      int row = mb + wr * 32 + r * 16 + l4 * 4 + reg;
#pragma unroll
      for (int n = 0; n < 4; ++n) {
        int col = nb + wc * 64 + n * 16 + l15;
        if (!GUARD || col < nout) {
          float v = acc[r][n][reg];
          if constexpr (BIAS) v += bias[col];
          Co[(size_t)row * nout + col] = v;
        }
      }
    }
}

// ---------------------------------------------------------------------------
// Deformable bilinear sampling + mask-weighted tap sum -> bf16 hi/lo output.
// One thread per (pixel, channel-quad); branchless clamp+valid.
// ---------------------------------------------------------------------------
__global__ __launch_bounds__(256) void sample_kernel(
    const float* __restrict__ val, const float* __restrict__ om,
    short* __restrict__ oh, short* __restrict__ ol) {
  int gid = blockIdx.x * 256 + threadIdx.x;  // over MM * 64
  int q = gid & 63;   // channel-quad
  int m = gid >> 6;   // pixel
  int g = q >> 4;     // group
  int w = m & 127, h = (m >> 7) & 127, n = m >> 14;
  const float* omp = om + m * OMW + g * 27;
  const float* vb = val + (n << 22) + (q << 2);
  float bx = (float)(w + 1), by = (float)(h + 1);
  float4 acc = make_float4(0.f, 0.f, 0.f, 0.f);

#pragma unroll
  for (int p = 0; p < PP; ++p) {
    float px = bx + 0.5f * ((float)(p % 3 - 1) + omp[2 * p]);
    float py = by + 0.5f * ((float)(p / 3 - 1) + omp[2 * p + 1]);
    float mk = omp[18 + p];
    float x0f = floorf(px), y0f = floorf(py);
    int x0 = (int)x0f, y0 = (int)y0f;
    float wx1 = px - x0f, wy1 = py - y0f;
    float wx0 = 1.f - wx1, wy0 = 1.f - wy1;
    float4 s = make_float4(0.f, 0.f, 0.f, 0.f);
#define CORNER(XC, YC, WT)                                            \
  {                                                                   \
    int xc = (XC), yc = (YC);                                         \
    int xi = min(max(xc, 1), 128), yi = min(max(yc, 1), 128);         \
    float wt = ((xc == xi) && (yc == yi)) ? (WT) : 0.f;               \
    const float4 v =                                                  \
        *(const float4*)&vb[(((yi - 1) << 7) + (xi - 1)) << 8];       \
    s.x += v.x * wt;                                                  \
    s.y += v.y * wt;                                                  \
    s.z += v.z * wt;                                                  \
    s.w += v.w * wt;                                                  \
  }
    CORNER(x0, y0, wx0 * wy0);
    CORNER(x0 + 1, y0, wx1 * wy0);
    CORNER(x0, y0 + 1, wx0 * wy1);
    CORNER(x0 + 1, y0 + 1, wx1 * wy1);
#undef CORNER
    acc.x += mk * s.x;
    acc.y += mk * s.y;
    acc.z += mk * s.z;
    acc.w += mk * s.w;
  }
  short4 hh, ll;
  split4(acc, &hh, &ll);
  *(short4*)&oh[((size_t)m << 8) + (q << 2)] = hh;
  *(short4*)&ol[((size_t)m << 8) + (q << 2)] = ll;
}

// ---------------------------------------------------------------------------
// Row LayerNorm (256 cols) + exact GELU. One wave per row.
// ---------------------------------------------------------------------------
__global__ __launch_bounds__(256) void ln_gelu_kernel(
    const float* __restrict__ x, const float* __restrict__ gam,
    const float* __restrict__ bet, float* __restrict__ y) {
  int row = blockIdx.x * 4 + (threadIdx.x >> 6);
  int lane = threadIdx.x & 63;
  const float* xr = x + (size_t)row * 256 + lane * 4;
  float4 v = *(const float4*)xr;
  float s = v.x + v.y + v.z + v.w;
  float ss = v.x * v.x + v.y * v.y + v.z * v.z + v.w * v.w;
#pragma unroll
  for (int m = 1; m < 64; m <<= 1) {
    s += __shfl_xor(s, m);
    ss += __shfl_xor(ss, m);
  }
  float mu = s * (1.f / 256.f);
  float var = ss * (1.f / 256.f) - mu * mu;
  float rs = rsqrtf(var + 1e-5f);
  float4 gg = *(const float4*)&gam[lane * 4];
  float4 bb = *(const float4*)&bet[lane * 4];
  float4 o;
#define GEL(FIELD)                                                   \
  {                                                                  \
    float t_ = (v.FIELD - mu) * rs * gg.FIELD + bb.FIELD;            \
    o.FIELD = 0.5f * t_ * (1.f + erff(t_ * 0.70710678118654752f));   \
  }
  GEL(x) GEL(y) GEL(z) GEL(w)
#undef GEL
  *(float4*)&y[(size_t)row * 256 + lane * 4] = o;
}

// ---------------------------------------------------------------------------
extern "C" void kernel_launch(void* const* d_in, const int* in_sizes, int n_in,
                              void* d_out, int out_size, void* d_ws,
                              size_t ws_size, hipStream_t stream) {
  (void)in_sizes;
  (void)n_in;
  (void)out_size;
  (void)ws_size;
  const float* sampled = (const float*)d_in[0];
  const float* ctxin = (const float*)d_in[1];
  const float* W_in = (const float*)d_in[2];
  const float* b_in = (const float*)d_in[3];
  const float* dwk = (const float*)d_in[4];
  const float* dwb = (const float*)d_in[5];
  const float* W_om = (const float*)d_in[6];
  const float* b_om = (const float*)d_in[7];
  const float* W_out = (const float*)d_in[8];
  const float* lng = (const float*)d_in[9];
  const float* lnb = (const float*)d_in[10];
  float* out = (float*)d_out;

  // Workspace layout (with lifetime-based aliasing):
  float* value = (float*)d_ws;                       // MM*256 f32
  float* omb = value + (size_t)MM * CC;              // MM*108 f32
  short* ctx_h = (short*)(omb + (size_t)MM * OMW);   // MM*256 bf16 (-> dcn_h)
  short* ctx_l = ctx_h + (size_t)MM * CC;            // MM*256 bf16 (-> dcn_l)
  short* xin_h = ctx_l + (size_t)MM * CC;            // MM*256 bf16
  short* xin_l = xin_h + (size_t)MM * CC;            // MM*256 bf16
  float* out_pre = (float*)(xin_l + (size_t)MM * CC);  // MM*256 f32
  short* Bth = (short*)(out_pre + (size_t)MM * CC);  // BTCOLS*256 bf16
  short* Btl = Bth + (size_t)BTCOLS * 256;
  short* dcn_h = ctx_h;  // ctx dead after om GEMM
  short* dcn_l = ctx_l;

  // 0. weight transpose + bf16 hi/lo split; input split
  prep_kernel<<<BTCOLS, 256, 0, stream>>>(W_in, W_om, W_out, Bth, Btl);
  split_kernel<<<MM * 64 / 256, 256, 0, stream>>>(sampled, xin_h, xin_l);
  // 1. depthwise conv -> ctx (bf16 hi/lo)
  dwconv_kernel<<<MM * 64 / 256, 256, 0, stream>>>(ctxin, dwk, dwb, ctx_h,
                                                   ctx_l);
  // 2. om = ctx @ W_om + b_om  (nout=108, guard)
  mgemm<true, true><<<MM / 64, 256, 0, stream>>>(
      ctx_h, ctx_l, Bth + 256 * 256, Btl + 256 * 256, b_om, omb, 0, OMW);
  // 3. value = sampled_feat @ W_in + b_in  (2 n-blocks)
  mgemm<false, true><<<2 * (MM / 64), 256, 0, stream>>>(
      xin_h, xin_l, Bth, Btl, b_in, value, 1, 256);
  // 4. deformable sampling -> dcn (bf16 hi/lo, reuses ctx buffers)
  sample_kernel<<<MM * 64 / 256, 256, 0, stream>>>(value, omb, dcn_h, dcn_l);
  // 5a. out_pre = dcn @ W_out
  mgemm<false, false><<<2 * (MM / 64), 256, 0, stream>>>(
      dcn_h, dcn_l, Bth + 384 * 256, Btl + 384 * 256, nullptr, out_pre, 1, 256);
  // 5b. out = GELU(LN(out_pre))
  ln_gelu_kernel<<<MM / 4, 256, 0, stream>>>(out_pre, lng, lnb, out);
}

// Round 7
// 239.220 us; speedup vs baseline: 1.1124x; 1.1124x over previous
//
#include <hip/hip_runtime.h>
#include <math.h>

// Problem constants
constexpr int NBATCH = 2, HH = 128, WW = 128, CC = 256;
constexpr int PP = 9, OMW = 108;            // om width = G*P*3 = 108
constexpr int MM = NBATCH * HH * WW;        // 32768 pixels
constexpr int BTCOLS = 640;                 // 256 (W_in) + 128 (W_om pad) + 256 (W_out)

using bf8 = __attribute__((ext_vector_type(8))) short;    // 8 bf16 = 4 VGPR
using f32x4 = __attribute__((ext_vector_type(4))) float;  // 4 f32 accum

__device__ __forceinline__ short f2bf(float x) {
  unsigned u = __builtin_bit_cast(unsigned, x);
  unsigned r = (u + 0x7fffu + ((u >> 16) & 1u)) >> 16;  // round-nearest-even
  return (short)r;
}
__device__ __forceinline__ float bf2f(short h) {
  unsigned u = ((unsigned)(unsigned short)h) << 16;
  return __builtin_bit_cast(float, u);
}
// [hi16(y) : hi16(x)] in one v_perm_b32
__device__ __forceinline__ unsigned pack_hi16(float x, float y) {
  return __builtin_amdgcn_perm(__builtin_bit_cast(unsigned, y),
                               __builtin_bit_cast(unsigned, x), 0x07060302u);
}
__device__ __forceinline__ float trunc_hi(float x) {
  return __builtin_bit_cast(float, __builtin_bit_cast(unsigned, x) & 0xFFFF0000u);
}

// ---------------------------------------------------------------------------
// Weight prep: transpose W (K-major -> col-major, K contiguous) and split
// f32 = hi(bf16) + lo(bf16). Cols [0,256)=W_in^T, [256,384)=W_om^T (pad 108
// ->128 with zeros), [384,640)=W_out^T. Row stride = 256 (K).
// ---------------------------------------------------------------------------
__global__ __launch_bounds__(256) void prep_kernel(
    const float* __restrict__ Win, const float* __restrict__ Wom,
    const float* __restrict__ Wout, short* __restrict__ Bh,
    short* __restrict__ Bl) {
  int gid = blockIdx.x * 256 + threadIdx.x;  // over BTCOLS*256
  int col = gid >> 8, k = gid & 255;
  float w;
  if (col < 256)
    w = Win[k * 256 + col];
  else if (col < 384) {
    int c = col - 256;
    w = (c < OMW) ? Wom[k * OMW + c] : 0.f;
  } else {
    int c = col - 384;
    w = Wout[k * 256 + c];
  }
  short h = f2bf(w);
  Bh[gid] = h;
  Bl[gid] = f2bf(w - bf2f(h));
}

// ---------------------------------------------------------------------------
// Depthwise 3x3 conv (pad 1) + bias -> f32.
// ---------------------------------------------------------------------------
__global__ __launch_bounds__(256) void dwconv_kernel(
    const float* __restrict__ x, const float* __restrict__ k,
    const float* __restrict__ b, float* __restrict__ y) {
  int gid = blockIdx.x * 256 + threadIdx.x;  // over MM * 64
  int q = gid & 63;
  int m = gid >> 6;
  int c = q * 4;
  int w = m & 127, h = (m >> 7) & 127, n = m >> 14;
  float4 acc = *(const float4*)&b[c];
#pragma unroll
  for (int dy = 0; dy < 3; ++dy) {
    int yy = h + dy - 1;
    if (yy < 0 || yy >= HH) continue;
#pragma unroll
    for (int dx = 0; dx < 3; ++dx) {
      int xx = w + dx - 1;
      if (xx < 0 || xx >= WW) continue;
      float4 v = *(const float4*)&x[(((size_t)n * HH + yy) * WW + xx) * CC + c];
      float4 kk = *(const float4*)&k[(dy * 3 + dx) * CC + c];
      acc.x += v.x * kk.x;
      acc.y += v.y * kk.y;
      acc.z += v.z * kk.z;
      acc.w += v.w * kk.w;
    }
  }
  *(float4*)&y[(size_t)m * CC + c] = acc;
}

// ---------------------------------------------------------------------------
// MFMA GEMM, bf16x3 split precision. A is f32, split hi/lo at LDS staging
// (truncate-split + v_perm pack). W pre-split/transposed (Bth/Btl).
// Co[M x nout] = A[M,256] @ W[256,nout] (+bias). BM=64, BN=128, BK=64.
// 256 threads = 4 waves (2m x 2n), each wave 32x64 = 2x4 frags of 16x16x32.
// LDS stride SK=68 shorts (136B) -> 2-way banks max (free). ~52KB -> 3 blk/CU.
// ---------------------------------------------------------------------------
template <bool GUARD, bool BIAS>
__global__ __launch_bounds__(256, 3) void mgemm(
    const float* __restrict__ Af, const short* __restrict__ Bth,
    const short* __restrict__ Btl, const float* __restrict__ bias,
    float* __restrict__ Co, int nshift, int nout) {
  constexpr int BM = 64, BN = 128, BK = 64, SK = 68;
  __shared__ __align__(16) short As[2][BM * SK];
  __shared__ __align__(16) short Bs[2][BN * SK];
  const int t = threadIdx.x;
  const int lane = t & 63, wid = t >> 6;
  const int wr = wid >> 1, wc = wid & 1;
  const int l15 = lane & 15, l4 = lane >> 4;
  const int mb = ((int)blockIdx.x >> nshift) * BM;
  const int nb = ((int)blockIdx.x & ((1 << nshift) - 1)) * BN;

  f32x4 acc[2][4];
#pragma unroll
  for (int r = 0; r < 2; ++r)
#pragma unroll
    for (int n = 0; n < 4; ++n) acc[r][n] = (f32x4){0.f, 0.f, 0.f, 0.f};

  for (int ks = 0; ks < 256; ks += BK) {
    // Stage A: 64 rows x 64 k f32 -> split hi/lo on the fly
#pragma unroll
    for (int i = 0; i < 4; ++i) {
      int idx = t + 256 * i;
      int row = idx >> 4, kq = (idx & 15) * 4;
      float4 v = *(const float4*)&Af[(size_t)(mb + row) * 256 + ks + kq];
      unsigned h01 = pack_hi16(v.x, v.y);
      unsigned h23 = pack_hi16(v.z, v.w);
      unsigned l01 = pack_hi16(v.x - trunc_hi(v.x), v.y - trunc_hi(v.y));
      unsigned l23 = pack_hi16(v.z - trunc_hi(v.z), v.w - trunc_hi(v.w));
      uint2 hw, lw;
      hw.x = h01; hw.y = h23; lw.x = l01; lw.y = l23;
      *(uint2*)&As[0][row * SK + kq] = hw;
      *(uint2*)&As[1][row * SK + kq] = lw;
    }
    // Stage B: 128 cols x 8 16B-chunks, hi+lo (pre-split)
#pragma unroll
    for (int i = 0; i < 4; ++i) {
      int idx = t + 256 * i;
      int col = idx >> 3, kq = (idx & 7) * 8;
      size_t g = (size_t)(nb + col) * 256 + ks + kq;
      *(bf8*)&Bs[0][col * SK + kq] = *(const bf8*)&Bth[g];
      *(bf8*)&Bs[1][col * SK + kq] = *(const bf8*)&Btl[g];
    }
    __syncthreads();
#pragma unroll
    for (int kk = 0; kk < 2; ++kk) {
      int ko = kk * 32 + l4 * 8;
      bf8 ah[2], al[2], bh[4], bl[4];
#pragma unroll
      for (int r = 0; r < 2; ++r) {
        int row = wr * 32 + r * 16 + l15;
        ah[r] = *(const bf8*)&As[0][row * SK + ko];
        al[r] = *(const bf8*)&As[1][row * SK + ko];
      }
#pragma unroll
      for (int n = 0; n < 4; ++n) {
        int col = wc * 64 + n * 16 + l15;
        bh[n] = *(const bf8*)&Bs[0][col * SK + ko];
        bl[n] = *(const bf8*)&Bs[1][col * SK + ko];
      }
#pragma unroll
      for (int r = 0; r < 2; ++r)
#pragma unroll
        for (int n = 0; n < 4; ++n) {
          acc[r][n] = __builtin_amdgcn_mfma_f32_16x16x32_bf16(al[r], bh[n],
                                                              acc[r][n], 0, 0, 0);
          acc[r][n] = __builtin_amdgcn_mfma_f32_16x16x32_bf16(ah[r], bl[n],
                                                              acc[r][n], 0, 0, 0);
          acc[r][n] = __builtin_amdgcn_mfma_f32_16x16x32_bf16(ah[r], bh[n],
                                                              acc[r][n], 0, 0, 0);
        }
    }
    __syncthreads();
  }

#pragma unroll
  for (int r = 0; r < 2; ++r)
#pragma unroll
    for (int reg = 0; reg < 4; ++reg) {
      int row = mb + wr * 32 + r * 16 + l4 * 4 + reg;
#pragma unroll
      for (int n = 0; n < 4; ++n) {
        int col = nb + wc * 64 + n * 16 + l15;
        if (!GUARD || col < nout) {
          float v = acc[r][n][reg];
          if constexpr (BIAS) v += bias[col];
          Co[(size_t)row * nout + col] = v;
        }
      }
    }
}

// ---------------------------------------------------------------------------
// Deformable sampling v3: shared 3x3 weight-window per (pixel, group).
// Block = 4 pixels x 4 groups x 16 channel-quads.
// Phase 1: one thread per tap (144 threads) folds mask*bilinear weights of
// all 4 corners into a 3x3 LDS window at padded base (w, h). Valid corners
// outside the window (requires |offset|>1; offsets are ~N(0,0.01)) set a
// fallback flag. Phase 2: each channel-thread does 9 fixed-position float4
// gathers weighted by the shared window. Exact fallback path kept.
// ---------------------------------------------------------------------------
__global__ __launch_bounds__(256) void sample_kernel(
    const float* __restrict__ val, const float* __restrict__ om,
    float* __restrict__ outp) {
  __shared__ float wwin[4][4][12];  // [pix][grp][ry*3+rx], padded 9->12
  __shared__ int fflag[4][4];
  const int t = threadIdx.x;
  const int m0 = (int)blockIdx.x * 4;

  if (t < 192) ((float*)wwin)[t] = 0.f;
  if (t < 16) ((int*)fflag)[t] = 0;
  __syncthreads();

  // Phase 1: per-tap weight accumulation
  if (t < 144) {
    int pix = t / 36, r = t % 36;
    int g = r / 9, p = r % 9;
    int m = m0 + pix;
    int w = m & 127, h = (m >> 7) & 127;
    const float* omp = om + (size_t)m * OMW + g * 27;
    float ox = omp[2 * p], oy = omp[2 * p + 1], mk = omp[18 + p];
    float px = (float)(w + 1) + 0.5f * ((float)(p % 3 - 1) + ox);
    float py = (float)(h + 1) + 0.5f * ((float)(p / 3 - 1) + oy);
    float x0f = floorf(px), y0f = floorf(py);
    int x0 = (int)x0f, y0 = (int)y0f;
    float wx1 = px - x0f, wy1 = py - y0f;
    float wx0 = 1.f - wx1, wy0 = 1.f - wy1;
#pragma unroll
    for (int j = 0; j < 2; ++j)
#pragma unroll
      for (int i = 0; i < 2; ++i) {
        int cx = x0 + i, cy = y0 + j;
        // nonzero contribution only for padded coords in [1,128]^2
        if (cx < 1 || cx > 128 || cy < 1 || cy > 128) continue;
        float cw = mk * (i ? wx1 : wx0) * (j ? wy1 : wy0);
        int rx = cx - w, ry = cy - h;  // rel to padded base (w, h)
        if ((unsigned)rx > 2u || (unsigned)ry > 2u)
          atomicOr(&fflag[pix][g], 1);
        else
          atomicAdd(&wwin[pix][g][ry * 3 + rx], cw);
      }
  }
  __syncthreads();

  // Phase 2: gather 3x3 window, weighted sum
  const int pix = t >> 6, g = (t >> 4) & 3, cq = t & 15;
  const int q = g * 16 + cq;
  const int m = m0 + pix;
  const int w = m & 127, h = (m >> 7) & 127, n = m >> 14;
  const float* vb = val + ((size_t)n << 22) + (q << 2);
  float4 acc = make_float4(0.f, 0.f, 0.f, 0.f);

  if (fflag[pix][g] == 0) {
#pragma unroll
    for (int ry = 0; ry < 3; ++ry)
#pragma unroll
      for (int rx = 0; rx < 3; ++rx) {
        float cw = wwin[pix][g][ry * 3 + rx];
        int xi = min(max(w - 1 + rx, 0), 127);
        int yi = min(max(h - 1 + ry, 0), 127);
        float4 v = *(const float4*)&vb[((yi << 7) + xi) << 8];
        acc.x += cw * v.x;
        acc.y += cw * v.y;
        acc.z += cw * v.z;
        acc.w += cw * v.w;
      }
  } else {
    // Exact fallback (rare): original 9-tap x 4-corner path
    const float* omp = om + (size_t)m * OMW + g * 27;
    float bx = (float)(w + 1), by = (float)(h + 1);
#pragma unroll
    for (int p = 0; p < PP; ++p) {
      float px = bx + 0.5f * ((float)(p % 3 - 1) + omp[2 * p]);
      float py = by + 0.5f * ((float)(p / 3 - 1) + omp[2 * p + 1]);
      float mk = omp[18 + p];
      float x0f = floorf(px), y0f = floorf(py);
      int x0 = (int)x0f, y0 = (int)y0f;
      float wx1 = px - x0f, wy1 = py - y0f;
      float wx0 = 1.f - wx1, wy0 = 1.f - wy1;
      float4 s = make_float4(0.f, 0.f, 0.f, 0.f);
#define CORNER(XC, YC, WT)                                            \
  {                                                                   \
    int xc = (XC), yc = (YC);                                         \
    int xi = min(max(xc, 1), 128), yi = min(max(yc, 1), 128);         \
    float wt = ((xc == xi) && (yc == yi)) ? (WT) : 0.f;               \
    const float4 v =                                                  \
        *(const float4*)&vb[(((yi - 1) << 7) + (xi - 1)) << 8];       \
    s.x += v.x * wt;                                                  \
    s.y += v.y * wt;                                                  \
    s.z += v.z * wt;                                                  \
    s.w += v.w * wt;                                                  \
  }
      CORNER(x0, y0, wx0 * wy0);
      CORNER(x0 + 1, y0, wx1 * wy0);
      CORNER(x0, y0 + 1, wx0 * wy1);
      CORNER(x0 + 1, y0 + 1, wx1 * wy1);
#undef CORNER
      acc.x += mk * s.x;
      acc.y += mk * s.y;
      acc.z += mk * s.z;
      acc.w += mk * s.w;
    }
  }
  *(float4*)&outp[((size_t)m << 8) + (q << 2)] = acc;
}

// ---------------------------------------------------------------------------
// Row LayerNorm (256 cols) + exact GELU. One wave per row.
// ---------------------------------------------------------------------------
__global__ __launch_bounds__(256) void ln_gelu_kernel(
    const float* __restrict__ x, const float* __restrict__ gam,
    const float* __restrict__ bet, float* __restrict__ y) {
  int row = blockIdx.x * 4 + (threadIdx.x >> 6);
  int lane = threadIdx.x & 63;
  const float* xr = x + (size_t)row * 256 + lane * 4;
  float4 v = *(const float4*)xr;
  float s = v.x + v.y + v.z + v.w;
  float ss = v.x * v.x + v.y * v.y + v.z * v.z + v.w * v.w;
#pragma unroll
  for (int m = 1; m < 64; m <<= 1) {
    s += __shfl_xor(s, m);
    ss += __shfl_xor(ss, m);
  }
  float mu = s * (1.f / 256.f);
  float var = ss * (1.f / 256.f) - mu * mu;
  float rs = rsqrtf(var + 1e-5f);
  float4 gg = *(const float4*)&gam[lane * 4];
  float4 bb = *(const float4*)&bet[lane * 4];
  float4 o;
#define GEL(FIELD)                                                   \
  {                                                                  \
    float t_ = (v.FIELD - mu) * rs * gg.FIELD + bb.FIELD;            \
    o.FIELD = 0.5f * t_ * (1.f + erff(t_ * 0.70710678118654752f));   \
  }
  GEL(x) GEL(y) GEL(z) GEL(w)
#undef GEL
  *(float4*)&y[(size_t)row * 256 + lane * 4] = o;
}

// ---------------------------------------------------------------------------
extern "C" void kernel_launch(void* const* d_in, const int* in_sizes, int n_in,
                              void* d_out, int out_size, void* d_ws,
                              size_t ws_size, hipStream_t stream) {
  (void)in_sizes;
  (void)n_in;
  (void)out_size;
  (void)ws_size;
  const float* sampled = (const float*)d_in[0];
  const float* ctxin = (const float*)d_in[1];
  const float* W_in = (const float*)d_in[2];
  const float* b_in = (const float*)d_in[3];
  const float* dwk = (const float*)d_in[4];
  const float* dwb = (const float*)d_in[5];
  const float* W_om = (const float*)d_in[6];
  const float* b_om = (const float*)d_in[7];
  const float* W_out = (const float*)d_in[8];
  const float* lng = (const float*)d_in[9];
  const float* lnb = (const float*)d_in[10];
  float* out = (float*)d_out;

  // Workspace (lifetime-aliased):
  float* value = (float*)d_ws;                      // MM*256 f32 (-> out_pre)
  float* omb = value + (size_t)MM * CC;             // MM*108 f32
  float* ctx = omb + (size_t)MM * OMW;              // MM*256 f32 (-> dcn)
  short* Bth = (short*)(ctx + (size_t)MM * CC);     // BTCOLS*256 bf16
  short* Btl = Bth + (size_t)BTCOLS * 256;
  float* dcn = ctx;        // ctx dead after om GEMM
  float* out_pre = value;  // value dead after sampling

  // 0. weight transpose + bf16 hi/lo split
  prep_kernel<<<BTCOLS, 256, 0, stream>>>(W_in, W_om, W_out, Bth, Btl);
  // 1. depthwise conv -> ctx (f32)
  dwconv_kernel<<<MM * 64 / 256, 256, 0, stream>>>(ctxin, dwk, dwb, ctx);
  // 2. om = ctx @ W_om + b_om  (nout=108, guard)
  mgemm<true, true><<<MM / 64, 256, 0, stream>>>(ctx, Bth + 256 * 256,
                                                 Btl + 256 * 256, b_om, omb, 0,
                                                 OMW);
  // 3. value = sampled_feat @ W_in + b_in  (2 n-blocks)
  mgemm<false, true><<<2 * (MM / 64), 256, 0, stream>>>(sampled, Bth, Btl,
                                                        b_in, value, 1, 256);
  // 4. deformable sampling -> dcn (f32)
  sample_kernel<<<MM / 4, 256, 0, stream>>>(value, omb, dcn);
  // 5a. out_pre = dcn @ W_out
  mgemm<false, false><<<2 * (MM / 64), 256, 0, stream>>>(
      dcn, Bth + 384 * 256, Btl + 384 * 256, nullptr, out_pre, 1, 256);
  // 5b. out = GELU(LN(out_pre))
  ln_gelu_kernel<<<MM / 4, 256, 0, stream>>>(out_pre, lng, lnb, out);
}

// Round 8
// 230.352 us; speedup vs baseline: 1.1552x; 1.0385x over previous
//
#include <hip/hip_runtime.h>
#include <math.h>

// Problem constants
constexpr int NBATCH = 2, HH = 128, WW = 128, CC = 256;
constexpr int PP = 9, OMW = 108;            // om width = G*P*3 = 108
constexpr int MM = NBATCH * HH * WW;        // 32768 pixels
constexpr int BTCOLS = 640;                 // 256 (W_in) + 128 (W_om pad) + 256 (W_out)

using bf8 = __attribute__((ext_vector_type(8))) short;    // 8 bf16 = 4 VGPR
using f32x4 = __attribute__((ext_vector_type(4))) float;  // 4 f32 accum

__device__ __forceinline__ short f2bf(float x) {
  unsigned u = __builtin_bit_cast(unsigned, x);
  unsigned r = (u + 0x7fffu + ((u >> 16) & 1u)) >> 16;  // round-nearest-even
  return (short)r;
}
__device__ __forceinline__ float bf2f(short h) {
  unsigned u = ((unsigned)(unsigned short)h) << 16;
  return __builtin_bit_cast(float, u);
}
// [hi16(y) : hi16(x)] in one v_perm_b32
__device__ __forceinline__ unsigned pack_hi16(float x, float y) {
  return __builtin_amdgcn_perm(__builtin_bit_cast(unsigned, y),
                               __builtin_bit_cast(unsigned, x), 0x07060302u);
}
__device__ __forceinline__ float trunc_hi(float x) {
  return __builtin_bit_cast(float, __builtin_bit_cast(unsigned, x) & 0xFFFF0000u);
}

// ---------------------------------------------------------------------------
// Weight prep: transpose W (K-major -> col-major, K contiguous) and split
// f32 = hi(bf16) + lo(bf16). Cols [0,256)=W_in^T, [256,384)=W_om^T (pad 108
// ->128 with zeros), [384,640)=W_out^T. Row stride = 256 (K).
// ---------------------------------------------------------------------------
__global__ __launch_bounds__(256) void prep_kernel(
    const float* __restrict__ Win, const float* __restrict__ Wom,
    const float* __restrict__ Wout, short* __restrict__ Bh,
    short* __restrict__ Bl) {
  int gid = blockIdx.x * 256 + threadIdx.x;  // over BTCOLS*256
  int col = gid >> 8, k = gid & 255;
  float w;
  if (col < 256)
    w = Win[k * 256 + col];
  else if (col < 384) {
    int c = col - 256;
    w = (c < OMW) ? Wom[k * OMW + c] : 0.f;
  } else {
    int c = col - 384;
    w = Wout[k * 256 + c];
  }
  short h = f2bf(w);
  Bh[gid] = h;
  Bl[gid] = f2bf(w - bf2f(h));
}

// ---------------------------------------------------------------------------
// Depthwise 3x3 conv (pad 1) + bias -> f32.
// ---------------------------------------------------------------------------
__global__ __launch_bounds__(256) void dwconv_kernel(
    const float* __restrict__ x, const float* __restrict__ k,
    const float* __restrict__ b, float* __restrict__ y) {
  int gid = blockIdx.x * 256 + threadIdx.x;  // over MM * 64
  int q = gid & 63;
  int m = gid >> 6;
  int c = q * 4;
  int w = m & 127, h = (m >> 7) & 127, n = m >> 14;
  float4 acc = *(const float4*)&b[c];
#pragma unroll
  for (int dy = 0; dy < 3; ++dy) {
    int yy = h + dy - 1;
    if (yy < 0 || yy >= HH) continue;
#pragma unroll
    for (int dx = 0; dx < 3; ++dx) {
      int xx = w + dx - 1;
      if (xx < 0 || xx >= WW) continue;
      float4 v = *(const float4*)&x[(((size_t)n * HH + yy) * WW + xx) * CC + c];
      float4 kk = *(const float4*)&k[(dy * 3 + dx) * CC + c];
      acc.x += v.x * kk.x;
      acc.y += v.y * kk.y;
      acc.z += v.z * kk.z;
      acc.w += v.w * kk.w;
    }
  }
  *(float4*)&y[(size_t)m * CC + c] = acc;
}

// ---------------------------------------------------------------------------
// MFMA GEMM, bf16x3 split precision. A f32 (hi/lo split at LDS staging via
// v_perm pack); W pre-split/transposed (Bth/Btl, K contiguous).
// Tiles: BM x BN x BK, 256 threads = 4 waves laid out WM x WN; per-wave
// R x C fragments of 16x16x32 (intensity = 3RC/(2R+2C) MFMA per ds_read).
// SK = BK+4 shorts: bank stride 34/18 -> <=2-way conflicts (free, m136);
// same 8B LDS alignment pattern as the validated R5/R7 kernel.
// LN variant (BM=64, BN=256=WN*64): fused LayerNorm + exact GELU epilogue.
// ---------------------------------------------------------------------------
template <int BM, int BN, int BK, int WM, int WN, bool GUARD, bool BIAS,
          bool LN>
__global__ __launch_bounds__(256, 2) void mgemm(
    const float* __restrict__ Af, const short* __restrict__ Bth,
    const short* __restrict__ Btl, const float* __restrict__ bias,
    float* __restrict__ Co, const float* __restrict__ lng,
    const float* __restrict__ lnb, int nshift, int nout) {
  constexpr int SK = BK + 4;
  constexpr int R = BM / (16 * WM), C = BN / (16 * WN);
  __shared__ __align__(16) short As[2][BM * SK];
  __shared__ __align__(16) short Bs[2][BN * SK];
  const int t = threadIdx.x;
  const int lane = t & 63, wid = t >> 6;
  const int wr = wid / WN, wc = wid % WN;
  const int l15 = lane & 15, l4 = lane >> 4;
  const int mb = ((int)blockIdx.x >> nshift) * BM;
  const int nb = ((int)blockIdx.x & ((1 << nshift) - 1)) * BN;

  f32x4 acc[R][C];
#pragma unroll
  for (int r = 0; r < R; ++r)
#pragma unroll
    for (int n = 0; n < C; ++n) acc[r][n] = (f32x4){0.f, 0.f, 0.f, 0.f};

  for (int ks = 0; ks < 256; ks += BK) {
    // Stage A: BM rows x BK k (f32 -> hi/lo bf16 on the fly)
#pragma unroll
    for (int i = 0; i < BM * BK / 4 / 256; ++i) {
      int idx = t + 256 * i;
      int row = idx / (BK / 4), kq = (idx % (BK / 4)) * 4;
      float4 v = *(const float4*)&Af[(size_t)(mb + row) * 256 + ks + kq];
      uint2 hw, lw;
      hw.x = pack_hi16(v.x, v.y);
      hw.y = pack_hi16(v.z, v.w);
      lw.x = pack_hi16(v.x - trunc_hi(v.x), v.y - trunc_hi(v.y));
      lw.y = pack_hi16(v.z - trunc_hi(v.z), v.w - trunc_hi(v.w));
      *(uint2*)&As[0][row * SK + kq] = hw;
      *(uint2*)&As[1][row * SK + kq] = lw;
    }
    // Stage B: BN cols x BK k (pre-split bf16 copy)
#pragma unroll
    for (int i = 0; i < BN * BK / 8 / 256; ++i) {
      int idx = t + 256 * i;
      int col = idx / (BK / 8), kq = (idx % (BK / 8)) * 8;
      size_t g = (size_t)(nb + col) * 256 + ks + kq;
      *(bf8*)&Bs[0][col * SK + kq] = *(const bf8*)&Bth[g];
      *(bf8*)&Bs[1][col * SK + kq] = *(const bf8*)&Btl[g];
    }
    __syncthreads();
#pragma unroll
    for (int kk = 0; kk < BK / 32; ++kk) {
      int ko = kk * 32 + l4 * 8;
      bf8 ah[R], al[R], bh[C], bl[C];
#pragma unroll
      for (int r = 0; r < R; ++r) {
        int row = (wr * R + r) * 16 + l15;
        ah[r] = *(const bf8*)&As[0][row * SK + ko];
        al[r] = *(const bf8*)&As[1][row * SK + ko];
      }
#pragma unroll
      for (int n = 0; n < C; ++n) {
        int col = (wc * C + n) * 16 + l15;
        bh[n] = *(const bf8*)&Bs[0][col * SK + ko];
        bl[n] = *(const bf8*)&Bs[1][col * SK + ko];
      }
#pragma unroll
      for (int r = 0; r < R; ++r)
#pragma unroll
        for (int n = 0; n < C; ++n) {
          acc[r][n] = __builtin_amdgcn_mfma_f32_16x16x32_bf16(al[r], bh[n],
                                                              acc[r][n], 0, 0, 0);
          acc[r][n] = __builtin_amdgcn_mfma_f32_16x16x32_bf16(ah[r], bl[n],
                                                              acc[r][n], 0, 0, 0);
          acc[r][n] = __builtin_amdgcn_mfma_f32_16x16x32_bf16(ah[r], bh[n],
                                                              acc[r][n], 0, 0, 0);
        }
    }
    __syncthreads();
  }

  if constexpr (LN) {
    // Full row (BN==256==nout) per block: LayerNorm + exact GELU fused.
    static_assert(WM == 1 && BM == 64, "LN layout");
    __shared__ float red_s[64][WN], red_ss[64][WN];
    __shared__ float mu_s[64], rs_s[64];
#pragma unroll
    for (int r = 0; r < R; ++r)
#pragma unroll
      for (int reg = 0; reg < 4; ++reg) {
        float s = 0.f, ss = 0.f;
#pragma unroll
        for (int n = 0; n < C; ++n) {
          float v = acc[r][n][reg];
          s += v;
          ss += v * v;
        }
#pragma unroll
        for (int mk = 1; mk < 16; mk <<= 1) {
          s += __shfl_xor(s, mk);
          ss += __shfl_xor(ss, mk);
        }
        if (l15 == 0) {
          int row = r * 16 + l4 * 4 + reg;
          red_s[row][wc] = s;
          red_ss[row][wc] = ss;
        }
      }
    __syncthreads();
    if (t < 64) {
      float s = 0.f, ss = 0.f;
#pragma unroll
      for (int p = 0; p < WN; ++p) {
        s += red_s[t][p];
        ss += red_ss[t][p];
      }
      float mu = s * (1.f / 256.f);
      float var = ss * (1.f / 256.f) - mu * mu;
      mu_s[t] = mu;
      rs_s[t] = rsqrtf(var + 1e-5f);
    }
    __syncthreads();
#pragma unroll
    for (int r = 0; r < R; ++r)
#pragma unroll
      for (int reg = 0; reg < 4; ++reg) {
        int rloc = r * 16 + l4 * 4 + reg;
        int row = mb + rloc;
        float mu = mu_s[rloc], rs = rs_s[rloc];
#pragma unroll
        for (int n = 0; n < C; ++n) {
          int col = (wc * C + n) * 16 + l15;
          float v = (acc[r][n][reg] - mu) * rs * lng[col] + lnb[col];
          Co[(size_t)row * 256 + col] =
              0.5f * v * (1.f + erff(v * 0.70710678118654752f));
        }
      }
  } else {
#pragma unroll
    for (int r = 0; r < R; ++r)
#pragma unroll
      for (int reg = 0; reg < 4; ++reg) {
        int row = mb + (wr * R + r) * 16 + l4 * 4 + reg;
#pragma unroll
        for (int n = 0; n < C; ++n) {
          int col = nb + (wc * C + n) * 16 + l15;
          if (!GUARD || col < nout) {
            float v = acc[r][n][reg];
            if constexpr (BIAS) v += bias[col];
            Co[(size_t)row * nout + col] = v;
          }
        }
      }
  }
}

// ---------------------------------------------------------------------------
// Deformable sampling v3: shared 3x3 weight-window per (pixel, group).
// Block = 4 pixels x 4 groups x 16 channel-quads. Phase 1: 144 tap-threads
// fold mask*bilinear corner weights into a 3x3 LDS window (fallback flag for
// out-of-window corners, |offset|>1 required -> effectively never). Phase 2:
// channel threads do 9 fixed-position float4 gathers. Exact fallback kept.
// ---------------------------------------------------------------------------
__global__ __launch_bounds__(256) void sample_kernel(
    const float* __restrict__ val, const float* __restrict__ om,
    float* __restrict__ outp) {
  __shared__ float wwin[4][4][12];
  __shared__ int fflag[4][4];
  const int t = threadIdx.x;
  const int m0 = (int)blockIdx.x * 4;

  if (t < 192) ((float*)wwin)[t] = 0.f;
  if (t < 16) ((int*)fflag)[t] = 0;
  __syncthreads();

  if (t < 144) {
    int pix = t / 36, r = t % 36;
    int g = r / 9, p = r % 9;
    int m = m0 + pix;
    int w = m & 127, h = (m >> 7) & 127;
    const float* omp = om + (size_t)m * OMW + g * 27;
    float ox = omp[2 * p], oy = omp[2 * p + 1], mk = omp[18 + p];
    float px = (float)(w + 1) + 0.5f * ((float)(p % 3 - 1) + ox);
    float py = (float)(h + 1) + 0.5f * ((float)(p / 3 - 1) + oy);
    float x0f = floorf(px), y0f = floorf(py);
    int x0 = (int)x0f, y0 = (int)y0f;
    float wx1 = px - x0f, wy1 = py - y0f;
    float wx0 = 1.f - wx1, wy0 = 1.f - wy1;
#pragma unroll
    for (int j = 0; j < 2; ++j)
#pragma unroll
      for (int i = 0; i < 2; ++i) {
        int cx = x0 + i, cy = y0 + j;
        if (cx < 1 || cx > 128 || cy < 1 || cy > 128) continue;
        float cw = mk * (i ? wx1 : wx0) * (j ? wy1 : wy0);
        int rx = cx - w, ry = cy - h;
        if ((unsigned)rx > 2u || (unsigned)ry > 2u)
          atomicOr(&fflag[pix][g], 1);
        else
          atomicAdd(&wwin[pix][g][ry * 3 + rx], cw);
      }
  }
  __syncthreads();

  const int pix = t >> 6, g = (t >> 4) & 3, cq = t & 15;
  const int q = g * 16 + cq;
  const int m = m0 + pix;
  const int w = m & 127, h = (m >> 7) & 127, n = m >> 14;
  const float* vb = val + ((size_t)n << 22) + (q << 2);
  float4 acc = make_float4(0.f, 0.f, 0.f, 0.f);

  if (fflag[pix][g] == 0) {
#pragma unroll
    for (int ry = 0; ry < 3; ++ry)
#pragma unroll
      for (int rx = 0; rx < 3; ++rx) {
        float cw = wwin[pix][g][ry * 3 + rx];
        int xi = min(max(w - 1 + rx, 0), 127);
        int yi = min(max(h - 1 + ry, 0), 127);
        float4 v = *(const float4*)&vb[((yi << 7) + xi) << 8];
        acc.x += cw * v.x;
        acc.y += cw * v.y;
        acc.z += cw * v.z;
        acc.w += cw * v.w;
      }
  } else {
    const float* omp = om + (size_t)m * OMW + g * 27;
    float bx = (float)(w + 1), by = (float)(h + 1);
#pragma unroll
    for (int p = 0; p < PP; ++p) {
      float px = bx + 0.5f * ((float)(p % 3 - 1) + omp[2 * p]);
      float py = by + 0.5f * ((float)(p / 3 - 1) + omp[2 * p + 1]);
      float mk = omp[18 + p];
      float x0f = floorf(px), y0f = floorf(py);
      int x0 = (int)x0f, y0 = (int)y0f;
      float wx1 = px - x0f, wy1 = py - y0f;
      float wx0 = 1.f - wx1, wy0 = 1.f - wy1;
      float4 s = make_float4(0.f, 0.f, 0.f, 0.f);
#define CORNER(XC, YC, WT)                                            \
  {                                                                   \
    int xc = (XC), yc = (YC);                                         \
    int xi = min(max(xc, 1), 128), yi = min(max(yc, 1), 128);         \
    float wt = ((xc == xi) && (yc == yi)) ? (WT) : 0.f;               \
    const float4 v =                                                  \
        *(const float4*)&vb[(((yi - 1) << 7) + (xi - 1)) << 8];       \
    s.x += v.x * wt;                                                  \
    s.y += v.y * wt;                                                  \
    s.z += v.z * wt;                                                  \
    s.w += v.w * wt;                                                  \
  }
      CORNER(x0, y0, wx0 * wy0);
      CORNER(x0 + 1, y0, wx1 * wy0);
      CORNER(x0, y0 + 1, wx0 * wy1);
      CORNER(x0 + 1, y0 + 1, wx1 * wy1);
#undef CORNER
      acc.x += mk * s.x;
      acc.y += mk * s.y;
      acc.z += mk * s.z;
      acc.w += mk * s.w;
    }
  }
  *(float4*)&outp[((size_t)m << 8) + (q << 2)] = acc;
}

// ---------------------------------------------------------------------------
extern "C" void kernel_launch(void* const* d_in, const int* in_sizes, int n_in,
                              void* d_out, int out_size, void* d_ws,
                              size_t ws_size, hipStream_t stream) {
  (void)in_sizes;
  (void)n_in;
  (void)out_size;
  (void)ws_size;
  const float* sampled = (const float*)d_in[0];
  const float* ctxin = (const float*)d_in[1];
  const float* W_in = (const float*)d_in[2];
  const float* b_in = (const float*)d_in[3];
  const float* dwk = (const float*)d_in[4];
  const float* dwb = (const float*)d_in[5];
  const float* W_om = (const float*)d_in[6];
  const float* b_om = (const float*)d_in[7];
  const float* W_out = (const float*)d_in[8];
  const float* lng = (const float*)d_in[9];
  const float* lnb = (const float*)d_in[10];
  float* out = (float*)d_out;

  // Workspace (lifetime-aliased):
  float* value = (float*)d_ws;                      // MM*256 f32
  float* omb = value + (size_t)MM * CC;             // MM*108 f32
  float* ctx = omb + (size_t)MM * OMW;              // MM*256 f32 (-> dcn)
  short* Bth = (short*)(ctx + (size_t)MM * CC);     // BTCOLS*256 bf16
  short* Btl = Bth + (size_t)BTCOLS * 256;
  float* dcn = ctx;  // ctx dead after om GEMM

  // 0. weight transpose + bf16 hi/lo split
  prep_kernel<<<BTCOLS, 256, 0, stream>>>(W_in, W_om, W_out, Bth, Btl);
  // 1. depthwise conv -> ctx (f32)
  dwconv_kernel<<<MM * 64 / 256, 256, 0, stream>>>(ctxin, dwk, dwb, ctx);
  // 2. om = ctx @ W_om + b_om  (BM=64 x BN=128, guard to 108, grid 512)
  mgemm<64, 128, 64, 2, 2, true, true, false><<<MM / 64, 256, 0, stream>>>(
      ctx, Bth + 256 * 256, Btl + 256 * 256, b_om, omb, nullptr, nullptr, 0,
      OMW);
  // 3. value = sampled_feat @ W_in + b_in (BM=128 x BN=128, grid 512)
  mgemm<128, 128, 64, 2, 2, false, true, false>
      <<<2 * (MM / 128), 256, 0, stream>>>(sampled, Bth, Btl, b_in, value,
                                           nullptr, nullptr, 1, 256);
  // 4. deformable sampling -> dcn (f32)
  sample_kernel<<<MM / 4, 256, 0, stream>>>(value, omb, dcn);
  // 5. out = GELU(LN(dcn @ W_out))  (BM=64 x BN=256 full row, fused epilogue)
  mgemm<64, 256, 32, 1, 4, false, false, true><<<MM / 64, 256, 0, stream>>>(
      dcn, Bth + 384 * 256, Btl + 384 * 256, nullptr, out, lng, lnb, 0, 256);
}